// Round 7
// baseline (183.362 us; speedup 1.0000x reference)
//
#include <hip/hip_runtime.h>

#define D    32       // feature dim (fixed)
#define BLK  256      // threads per block (4 waves, 64 i-rows per block)
#define BLKP 64       // precompute block (wide grid: latency-bound kernel)
#define NCH  16       // j-chunks per batch -> grid.y
#define SJ   128      // j-rows staged in LDS per stage (8 MFMA tiles)

#define LOG2E 1.44269504088896340736f

typedef short  short8  __attribute__((ext_vector_type(8)));
typedef float  floatx4 __attribute__((ext_vector_type(4)));
typedef float  v2f     __attribute__((ext_vector_type(2)));

__device__ __forceinline__ short f2bf(float v) {       // fp32 -> bf16 (RTNE-ish)
    union { float f; unsigned u; } x; x.f = v;
    unsigned r = x.u + 0x7fffu + ((x.u >> 16) & 1u);
    return (short)(r >> 16);
}
__device__ __forceinline__ float bf2f(short h) {
    union { float f; unsigned u; } x;
    x.u = ((unsigned)(unsigned short)h) << 16;
    return x.f;
}
__device__ __forceinline__ float fast_exp2(float x) {
#if __has_builtin(__builtin_amdgcn_exp2f)
    return __builtin_amdgcn_exp2f(x);
#else
    return exp2f(x);
#endif
}

// ---------------------------------------------------------------------------
// Kernel P: per-row precompute + zero-init + global bf16 hi/lo split of fea2
// (fragment-major, unchanged from baseline) + j/i scalar arrays:
//   xp4[r] = (20*px, 20*py, 20*pz, -log2e*|20*p|^2)   [w pre-negated]
//   mfn[r] = -log2e*|fea2_r|^2                        [pre-negated]
//   f1n[r] =  log2e*|fea1_r|^2
// ---------------------------------------------------------------------------
__global__ __launch_bounds__(BLKP) void precompute_kernel(
    const float* __restrict__ points,
    const float* __restrict__ fea1,
    const float* __restrict__ fea2,
    float4* __restrict__ xp4,
    float* __restrict__ f1n,
    float* __restrict__ mfn,
    short* __restrict__ f2hi,
    short* __restrict__ f2lo,
    float* __restrict__ acc,
    float* __restrict__ out,
    int BN, int Bsz)
{
    int r = blockIdx.x * BLKP + threadIdx.x;
    if (r < Bsz) out[r] = 0.0f;
    if (r >= BN) return;
#pragma unroll
    for (int s = 0; s < 5; ++s) acc[s * BN + r] = 0.0f;

    const float s20 = 20.0f;                 // 1/SIGMA
    float x = points[3*r+0] * s20;
    float y = points[3*r+1] * s20;
    float z = points[3*r+2] * s20;
    float4 v; v.x = x; v.y = y; v.z = z;
    v.w = -((x*x + y*y + z*z) * LOG2E);      // pre-negated
    xp4[r] = v;

    // f1 norm
    const float4* p1 = (const float4*)(fea1 + (size_t)r * D);
    float n1 = 0.f;
#pragma unroll
    for (int k = 0; k < D/4; ++k) {
        float4 a = p1[k];
        n1 = fmaf(a.x,a.x, fmaf(a.y,a.y, fmaf(a.z,a.z, fmaf(a.w,a.w, n1))));
    }
    f1n[r] = n1 * LOG2E;

    // f2: norm + hi/lo split, scattered fragment-major
    const int t = r >> 4;                    // global 16-row tile id
    const int m = r & 15;
    const float* p2 = fea2 + (size_t)r * D;
    float n2 = 0.f;
#pragma unroll
    for (int q = 0; q < 4; ++q) {
        float4 v0 = *(const float4*)(p2 + q*8);
        float4 v1 = *(const float4*)(p2 + q*8 + 4);
        float e[8] = {v0.x,v0.y,v0.z,v0.w,v1.x,v1.y,v1.z,v1.w};
        short8 h, l;
#pragma unroll
        for (int k = 0; k < 8; ++k) {
            n2 = fmaf(e[k], e[k], n2);
            short hh = f2bf(e[k]);
            h[k] = hh;
            l[k] = f2bf(e[k] - bf2f(hh));
        }
        size_t off = ((size_t)t * 64 + m + 16*q) * 8;
        *(short8*)&f2hi[off] = h;
        *(short8*)&f2lo[off] = l;
    }
    mfn[r] = -(n2 * LOG2E);                  // pre-negated
}

// ---------------------------------------------------------------------------
// Kernel A: pair loop, SWAPPED MFMA mapping (verified in R3) with the two R3
// overheads fixed:
//   A = f1 (register frags), B = f2 (LDS frags) -> C col = lane&15 = j,
//   rows = q*4+r = i. Each lane: ONE j, 4 i's per tile.
//   Per-tile LDS: 2 frag b128 (24cy) + 1 sXJ b128 (2-way, ~free) + 1 sFN b32
//   (broadcast) ~= 42 cy vs 88 cy of the R6 mapping (j-scalar broadcasts
//   were 64 cy of 16-way-redundant reads). LDS pipe is the measured binder
//   (~21us of pair's ~28us; VALU is only ~5us -- it is per-SIMD x4).
//   Reduce over the 16 m-lanes via ONE xor-8 fold + LDS transpose (aliasing
//   the dead fragment buffers) -- ~190cy/wave vs R3's ~480cy shuffle tree.
//   Registers: hot set ~64; forced __launch_bounds__(256,8) keeps 8 w/SIMD
//   (>64 VGPR would 2-pass the 2048-block grid -- R3's suspected cliff).
//   Per-pair arithmetic bit-identical to R6 (same fma/exp chains).
// ---------------------------------------------------------------------------
__global__ __launch_bounds__(BLK, 8) void pair_kernel(
    const float* __restrict__ fea1,
    const short* __restrict__ f2hi,
    const short* __restrict__ f2lo,
    const float4* __restrict__ xp4,
    const float* __restrict__ f1n,
    const float* __restrict__ mfn,
    float* __restrict__ acc,
    int N, int BN)
{
    __shared__ __align__(16) char smem[8192 + 8192 + 2048 + 512]; // 18.9 KB
    short*  sHi = (short*)smem;                 // 8 KB fragment-major
    short*  sLo = (short*)(smem + 8192);        // 8 KB
    float4* sXJ = (float4*)(smem + 16384);      // 2 KB (x,y,z,-w)
    float*  sFN = (float*)(smem + 18432);       // 512 B (-f2n)
    float*  sRED = (float*)smem;                // reduce phase reuse (12.8 KB)

    const int tid  = threadIdx.x;
    const int lane = tid & 63;
    const int wv   = tid >> 6;
    const int m    = lane & 15;        // j-within-tile (C col); f1 A-frag row
    const int q    = lane >> 4;        // k-octet; i-quad selector

    const int ibpb  = N / 64;          // i-blocks per batch
    const int b     = blockIdx.x / ibpb;
    const int ibase = blockIdx.x * 64 + wv * 16;
    const int JCH   = N / NCH;
    const int jc0   = blockIdx.y * JCH;

    // ---- A fragments: f1 rows of this wave's 16 i's, split hi/lo ----
    const float* f1p = fea1 + (size_t)(ibase + m) * D + q * 8;
    float4 bv0 = *(const float4*)(f1p);
    float4 bv1 = *(const float4*)(f1p + 4);
    float bfv[8] = {bv0.x,bv0.y,bv0.z,bv0.w,bv1.x,bv1.y,bv1.z,bv1.w};
    short8 F1hi, F1lo;
#pragma unroll
    for (int k = 0; k < 8; ++k) {
        short h = f2bf(bfv[k]);
        F1hi[k] = h;
        F1lo[k] = f2bf(bfv[k] - bf2f(h));
    }

    // ---- per-i constants for this lane's 4 output rows (i = ibase+q*4+r) ----
    const float L2 = 2.0f * LOG2E;
    v2f vxx[2], vxy[2], vxz[2], vmw[2], vnf[2];
#pragma unroll
    for (int g = 0; g < 2; ++g) {
        int i0 = ibase + q*4 + g*2;
        float4 a0 = xp4[i0];
        float4 a1 = xp4[i0 + 1];
        v2f t;
        t.x = a0.x * L2; t.y = a1.x * L2; vxx[g] = t;
        t.x = a0.y * L2; t.y = a1.y * L2; vxy[g] = t;
        t.x = a0.z * L2; t.y = a1.z * L2; vxz[g] = t;
        t.x = a0.w;      t.y = a1.w;      vmw[g] = t;   // already -w
        t.x = -f1n[i0];  t.y = -f1n[i0+1]; vnf[g] = t;
    }
    v2f vL2 = {L2, L2};

    // accumulators: 5 sums x 2 i-pairs (g=0: rows q*4+{0,1}; g=1: {2,3})
    v2f sA2[2]  = {{0.f,0.f},{0.f,0.f}};
    v2f sB2[2]  = {{0.f,0.f},{0.f,0.f}};
    v2f s2a2[2] = {{0.f,0.f},{0.f,0.f}};
    v2f s2b2[2] = {{0.f,0.f},{0.f,0.f}};
    v2f sab2[2] = {{0.f,0.f},{0.f,0.f}};

    const short*  gHi = f2hi + ((size_t)(b * N + jc0) >> 4) * 512;
    const short*  gLo = f2lo + ((size_t)(b * N + jc0) >> 4) * 512;
    const float4* xpb = xp4 + (size_t)b * N + jc0;
    const float*  fnb = mfn + (size_t)b * N + jc0;

    for (int s = 0; s < JCH; s += SJ) {
        // ---- stage: pure contiguous copy (8 KB hi + 8 KB lo + scalars) ----
        const uint4* srcH = (const uint4*)(gHi + (size_t)(s >> 4) * 512);
        const uint4* srcL = (const uint4*)(gLo + (size_t)(s >> 4) * 512);
        uint4* dstH = (uint4*)sHi;
        uint4* dstL = (uint4*)sLo;
        dstH[tid]       = srcH[tid];
        dstH[tid + 256] = srcH[tid + 256];
        dstL[tid]       = srcL[tid];
        dstL[tid + 256] = srcL[tid + 256];
        if (tid < SJ) {
            sXJ[tid] = xpb[s + tid];
            sFN[tid] = fnb[s + tid];
        }
        __syncthreads();

        // ---- compute: 8 16x16 pair tiles ----
#pragma unroll 2
        for (int jt8 = 0; jt8 < SJ/16; ++jt8) {
            const short8 Ahi = *(const short8*)&sHi[(jt8 * 64 + lane) * 8];
            const short8 Alo = *(const short8*)&sLo[(jt8 * 64 + lane) * 8];
            floatx4 c = {0.f, 0.f, 0.f, 0.f};
            c = __builtin_amdgcn_mfma_f32_16x16x32_bf16(F1hi, Ahi, c, 0, 0, 0);
            c = __builtin_amdgcn_mfma_f32_16x16x32_bf16(F1hi, Alo, c, 0, 0, 0);
            c = __builtin_amdgcn_mfma_f32_16x16x32_bf16(F1lo, Ahi, c, 0, 0, 0);

            const int jl = jt8 * 16 + m;       // this lane's single j
            float4 xj = sXJ[jl];               // (x,y,z,-w)
            float fnj = sFN[jl];               // -f2n
            v2f xjx = {xj.x, xj.x};
            v2f xjy = {xj.y, xj.y};
            v2f xjz = {xj.z, xj.z};
            v2f xjw = {xj.w, xj.w};
            v2f fn2 = {fnj, fnj};

#pragma unroll
            for (int g = 0; g < 2; ++g) {
                v2f c2; c2.x = c[2*g]; c2.y = c[2*g + 1];
                v2f t0 = __builtin_elementwise_fma(xjx, vxx[g], vmw[g]);
                t0 = __builtin_elementwise_fma(xjy, vxy[g], t0);
                t0 = __builtin_elementwise_fma(xjz, vxz[g], t0);
                v2f aL = t0 + xjw;                               // log2 spatial
                v2f bL = __builtin_elementwise_fma(c2, vL2, vnf[g] + fn2);
                v2f ea; ea.x = fast_exp2(aL.x); ea.y = fast_exp2(aL.y);
                v2f eb; eb.x = fast_exp2(bL.x); eb.y = fast_exp2(bL.y);
                sA2[g] += ea;
                sB2[g] += eb;
                s2a2[g] = __builtin_elementwise_fma(ea, ea, s2a2[g]);
                s2b2[g] = __builtin_elementwise_fma(eb, eb, s2b2[g]);
                sab2[g] = __builtin_elementwise_fma(ea, eb, sab2[g]);
            }
        }
        __syncthreads();
    }

    // ---- reduce over m: one xor-8 fold, then LDS transpose ----
#define F8(v) do { v.x += __shfl_xor(v.x, 8); v.y += __shfl_xor(v.y, 8); } while (0)
    F8(sA2[0]);  F8(sA2[1]);
    F8(s2a2[0]); F8(s2a2[1]);
    F8(sB2[0]);  F8(sB2[1]);
    F8(s2b2[0]); F8(s2b2[1]);
    F8(sab2[0]); F8(sab2[1]);
#undef F8

    // sRED layout: row rr = (wv*4+q)*5 + qty, 40 floats/row (160 B, padded
    // for bank spread), col m*4: float4 = i rows (q*4 .. q*4+3).
    if (m < 8) {
        float* base = sRED + (size_t)((wv*4 + q) * 5) * 40 + m * 4;
        float4 t;
        t.x=sA2[0].x;  t.y=sA2[0].y;  t.z=sA2[1].x;  t.w=sA2[1].y;  *(float4*)(base + 0*40) = t;
        t.x=s2a2[0].x; t.y=s2a2[0].y; t.z=s2a2[1].x; t.w=s2a2[1].y; *(float4*)(base + 1*40) = t;
        t.x=sB2[0].x;  t.y=sB2[0].y;  t.z=sB2[1].x;  t.w=sB2[1].y;  *(float4*)(base + 2*40) = t;
        t.x=s2b2[0].x; t.y=s2b2[0].y; t.z=s2b2[1].x; t.w=s2b2[1].y; *(float4*)(base + 3*40) = t;
        t.x=sab2[0].x; t.y=sab2[0].y; t.z=sab2[1].x; t.w=sab2[1].y; *(float4*)(base + 4*40) = t;
    }
    __syncthreads();

    if (tid < 80) {                            // 16 i-quads x 5 quantities
        const float* rbase = sRED + (size_t)tid * 40;
        float4 sm = *(const float4*)(rbase);
#pragma unroll
        for (int mm = 1; mm < 8; ++mm) {
            float4 t = *(const float4*)(rbase + mm * 4);
            sm.x += t.x; sm.y += t.y; sm.z += t.z; sm.w += t.w;
        }
        int iq  = tid / 5;
        int qty = tid - iq * 5;
        int row = blockIdx.x * 64 + iq * 4;
        float* ap = acc + (size_t)qty * BN + row;
        atomicAdd(ap + 0, sm.x);
        atomicAdd(ap + 1, sm.y);
        atomicAdd(ap + 2, sm.z);
        atomicAdd(ap + 3, sm.w);
    }
}

// ---------------------------------------------------------------------------
// Kernel B: combine per-row sums, weight, reduce into out[b] (out zeroed by P).
//   out[b] = sum_i w_i * ( S2a/A^2 - 2*Sab/(A*B) + S2b/B^2 )
// ---------------------------------------------------------------------------
__global__ __launch_bounds__(BLK) void finalize_kernel(
    const float* __restrict__ acc,
    const float* __restrict__ weights,
    float* __restrict__ out,
    int N, int BN)
{
    int row = blockIdx.x * BLK + threadIdx.x;
    int b   = (blockIdx.x * BLK) / N;

    float A   = acc[0*BN + row];
    float S2a = acc[1*BN + row];
    float Bt  = acc[2*BN + row];
    float S2b = acc[3*BN + row];
    float Sab = acc[4*BN + row];
    float invA = 1.0f / A;
    float invB = 1.0f / Bt;
    float val  = S2a*invA*invA - 2.0f*Sab*invA*invB + S2b*invB*invB;
    float sum  = weights[row] * val;

    __shared__ float red[BLK/64];
    for (int off = 32; off > 0; off >>= 1)
        sum += __shfl_down(sum, off);
    if ((threadIdx.x & 63) == 0) red[threadIdx.x >> 6] = sum;
    __syncthreads();
    if (threadIdx.x == 0) {
        float s = 0.f;
#pragma unroll
        for (int w = 0; w < BLK/64; ++w) s += red[w];
        atomicAdd(&out[b], s);
    }
}

// ---------------------------------------------------------------------------
extern "C" void kernel_launch(void* const* d_in, const int* in_sizes, int n_in,
                              void* d_out, int out_size, void* d_ws, size_t ws_size,
                              hipStream_t stream) {
    const float* points  = (const float*)d_in[0];
    const float* fea1    = (const float*)d_in[1];
    const float* fea2    = (const float*)d_in[2];
    const float* weights = (const float*)d_in[3];
    float* out = (float*)d_out;

    int B  = out_size;          // 2
    int BN = in_sizes[3];       // B*N = 8192
    int N  = BN / B;            // 4096

    // workspace (bytes):
    //   acc  : 5*BN*4   @ 0
    //   xp4  : 4*BN*4   @ 5*BN*4
    //   mfn  : BN*4     @ 9*BN*4
    //   f1n  : BN*4     @ 10*BN*4
    //   f2hi : BN*D*2   @ 11*BN*4
    //   f2lo : BN*D*2
    float*  acc  = (float*)d_ws;
    float4* xp4  = (float4*)((char*)d_ws + (size_t)5  * BN * 4);
    float*  mfn  = (float*)((char*)d_ws + (size_t)9  * BN * 4);
    float*  f1n  = (float*)((char*)d_ws + (size_t)10 * BN * 4);
    short*  f2hi = (short*)((char*)d_ws + (size_t)11 * BN * 4);
    short*  f2lo = f2hi + (size_t)BN * D;

    precompute_kernel<<<dim3((BN + BLKP - 1) / BLKP), dim3(BLKP), 0, stream>>>(
        points, fea1, fea2, xp4, f1n, mfn, f2hi, f2lo, acc, out, BN, B);

    dim3 grid(BN / 64, NCH);    // 128 x 16 = 2048 blocks (8 blocks/CU)
    pair_kernel<<<grid, dim3(BLK), 0, stream>>>(
        fea1, f2hi, f2lo, xp4, f1n, mfn, acc, N, BN);

    finalize_kernel<<<dim3(BN / BLK), dim3(BLK), 0, stream>>>(acc, weights, out, N, BN);
}

// Round 8
// 87.057 us; speedup vs baseline: 2.1062x; 2.1062x over previous
//
#include <hip/hip_runtime.h>

#define D    32       // feature dim (fixed)
#define BLK  256      // threads per block (4 waves, 64 i-rows per block)
#define BLKP 64       // precompute block (wide grid: latency-bound kernel)
#define NCH  16       // j-chunks per batch -> grid.y
#define SJ   128      // j-rows staged in LDS per stage (8 MFMA tiles)

#define LOG2E 1.44269504088896340736f

typedef short  short8  __attribute__((ext_vector_type(8)));
typedef float  floatx4 __attribute__((ext_vector_type(4)));
typedef float  v2f     __attribute__((ext_vector_type(2)));

__device__ __forceinline__ short f2bf(float v) {       // fp32 -> bf16 (RTNE-ish)
    union { float f; unsigned u; } x; x.f = v;
    unsigned r = x.u + 0x7fffu + ((x.u >> 16) & 1u);
    return (short)(r >> 16);
}
__device__ __forceinline__ float bf2f(short h) {
    union { float f; unsigned u; } x;
    x.u = ((unsigned)(unsigned short)h) << 16;
    return x.f;
}
__device__ __forceinline__ float fast_exp2(float x) {
#if __has_builtin(__builtin_amdgcn_exp2f)
    return __builtin_amdgcn_exp2f(x);
#else
    return exp2f(x);
#endif
}

// ---------------------------------------------------------------------------
// Kernel P: per-row precompute + zero-init + global bf16 hi/lo split of fea2
// (fragment-major, unchanged from baseline) + j/i scalar arrays:
//   xp4[r] = (20*px, 20*py, 20*pz, -log2e*|20*p|^2)   [w pre-negated]
//   mfn[r] = -log2e*|fea2_r|^2                        [pre-negated]
//   f1n[r] =  log2e*|fea1_r|^2
// ---------------------------------------------------------------------------
__global__ __launch_bounds__(BLKP) void precompute_kernel(
    const float* __restrict__ points,
    const float* __restrict__ fea1,
    const float* __restrict__ fea2,
    float4* __restrict__ xp4,
    float* __restrict__ f1n,
    float* __restrict__ mfn,
    short* __restrict__ f2hi,
    short* __restrict__ f2lo,
    float* __restrict__ acc,
    float* __restrict__ out,
    int BN, int Bsz)
{
    int r = blockIdx.x * BLKP + threadIdx.x;
    if (r < Bsz) out[r] = 0.0f;
    if (r >= BN) return;
#pragma unroll
    for (int s = 0; s < 5; ++s) acc[s * BN + r] = 0.0f;

    const float s20 = 20.0f;                 // 1/SIGMA
    float x = points[3*r+0] * s20;
    float y = points[3*r+1] * s20;
    float z = points[3*r+2] * s20;
    float4 v; v.x = x; v.y = y; v.z = z;
    v.w = -((x*x + y*y + z*z) * LOG2E);      // pre-negated
    xp4[r] = v;

    // f1 norm
    const float4* p1 = (const float4*)(fea1 + (size_t)r * D);
    float n1 = 0.f;
#pragma unroll
    for (int k = 0; k < D/4; ++k) {
        float4 a = p1[k];
        n1 = fmaf(a.x,a.x, fmaf(a.y,a.y, fmaf(a.z,a.z, fmaf(a.w,a.w, n1))));
    }
    f1n[r] = n1 * LOG2E;

    // f2: norm + hi/lo split, scattered fragment-major
    const int t = r >> 4;                    // global 16-row tile id
    const int m = r & 15;
    const float* p2 = fea2 + (size_t)r * D;
    float n2 = 0.f;
#pragma unroll
    for (int q = 0; q < 4; ++q) {
        float4 v0 = *(const float4*)(p2 + q*8);
        float4 v1 = *(const float4*)(p2 + q*8 + 4);
        float e[8] = {v0.x,v0.y,v0.z,v0.w,v1.x,v1.y,v1.z,v1.w};
        short8 h, l;
#pragma unroll
        for (int k = 0; k < 8; ++k) {
            n2 = fmaf(e[k], e[k], n2);
            short hh = f2bf(e[k]);
            h[k] = hh;
            l[k] = f2bf(e[k] - bf2f(hh));
        }
        size_t off = ((size_t)t * 64 + m + 16*q) * 8;
        *(short8*)&f2hi[off] = h;
        *(short8*)&f2lo[off] = l;
    }
    mfn[r] = -(n2 * LOG2E);                  // pre-negated
}

// ---------------------------------------------------------------------------
// Kernel A: pair loop, SWAPPED MFMA mapping -- identical to R7 EXCEPT the
// launch bounds: __launch_bounds__(BLK) with NO min-waves arg.
//   R7 POST-MORTEM: __launch_bounds__(256,8) capped VGPR at 64 < the ~85-reg
//   live set of this mapping -> compiler spilled the hot loop to scratch
//   (VGPR_Count=32, FETCH 228MB + WRITE 230MB of scratch traffic/dispatch,
//   pair 120us). Uncapped: ~90 VGPR, zero spill, ~5 waves/SIMD -- latency
//   coverage ~300 issue-cy vs ~250cy chain, adequate; and the LDS pipe (the
//   measured binder) only cares about total work per CU, not wave count.
//   Mapping recap: A=f1 (reg frags), B=f2 (LDS frags); C col=lane&15=j,
//   rows=q*4+r=i. Per-tile LDS: 2 frag b128 + 1 sXJ b128 (2-way, free) +
//   1 sFN b32 (broadcast) ~= 42cy vs 88cy of the R6 mapping. Reduce: one
//   xor-8 fold + LDS transpose (correctness HW-verified in R7, absmax=0).
// ---------------------------------------------------------------------------
__global__ __launch_bounds__(BLK) void pair_kernel(
    const float* __restrict__ fea1,
    const short* __restrict__ f2hi,
    const short* __restrict__ f2lo,
    const float4* __restrict__ xp4,
    const float* __restrict__ f1n,
    const float* __restrict__ mfn,
    float* __restrict__ acc,
    int N, int BN)
{
    __shared__ __align__(16) char smem[8192 + 8192 + 2048 + 512]; // 18.9 KB
    short*  sHi = (short*)smem;                 // 8 KB fragment-major
    short*  sLo = (short*)(smem + 8192);        // 8 KB
    float4* sXJ = (float4*)(smem + 16384);      // 2 KB (x,y,z,-w)
    float*  sFN = (float*)(smem + 18432);       // 512 B (-f2n)
    float*  sRED = (float*)smem;                // reduce phase reuse (12.8 KB)

    const int tid  = threadIdx.x;
    const int lane = tid & 63;
    const int wv   = tid >> 6;
    const int m    = lane & 15;        // j-within-tile (C col); f1 A-frag row
    const int q    = lane >> 4;        // k-octet; i-quad selector

    const int ibpb  = N / 64;          // i-blocks per batch
    const int b     = blockIdx.x / ibpb;
    const int ibase = blockIdx.x * 64 + wv * 16;
    const int JCH   = N / NCH;
    const int jc0   = blockIdx.y * JCH;

    // ---- A fragments: f1 rows of this wave's 16 i's, split hi/lo ----
    const float* f1p = fea1 + (size_t)(ibase + m) * D + q * 8;
    float4 bv0 = *(const float4*)(f1p);
    float4 bv1 = *(const float4*)(f1p + 4);
    float bfv[8] = {bv0.x,bv0.y,bv0.z,bv0.w,bv1.x,bv1.y,bv1.z,bv1.w};
    short8 F1hi, F1lo;
#pragma unroll
    for (int k = 0; k < 8; ++k) {
        short h = f2bf(bfv[k]);
        F1hi[k] = h;
        F1lo[k] = f2bf(bfv[k] - bf2f(h));
    }

    // ---- per-i constants for this lane's 4 output rows (i = ibase+q*4+r) ----
    const float L2 = 2.0f * LOG2E;
    v2f vxx[2], vxy[2], vxz[2], vmw[2], vnf[2];
#pragma unroll
    for (int g = 0; g < 2; ++g) {
        int i0 = ibase + q*4 + g*2;
        float4 a0 = xp4[i0];
        float4 a1 = xp4[i0 + 1];
        v2f t;
        t.x = a0.x * L2; t.y = a1.x * L2; vxx[g] = t;
        t.x = a0.y * L2; t.y = a1.y * L2; vxy[g] = t;
        t.x = a0.z * L2; t.y = a1.z * L2; vxz[g] = t;
        t.x = a0.w;      t.y = a1.w;      vmw[g] = t;   // already -w
        t.x = -f1n[i0];  t.y = -f1n[i0+1]; vnf[g] = t;
    }
    v2f vL2 = {L2, L2};

    // accumulators: 5 sums x 2 i-pairs (g=0: rows q*4+{0,1}; g=1: {2,3})
    v2f sA2[2]  = {{0.f,0.f},{0.f,0.f}};
    v2f sB2[2]  = {{0.f,0.f},{0.f,0.f}};
    v2f s2a2[2] = {{0.f,0.f},{0.f,0.f}};
    v2f s2b2[2] = {{0.f,0.f},{0.f,0.f}};
    v2f sab2[2] = {{0.f,0.f},{0.f,0.f}};

    const short*  gHi = f2hi + ((size_t)(b * N + jc0) >> 4) * 512;
    const short*  gLo = f2lo + ((size_t)(b * N + jc0) >> 4) * 512;
    const float4* xpb = xp4 + (size_t)b * N + jc0;
    const float*  fnb = mfn + (size_t)b * N + jc0;

    for (int s = 0; s < JCH; s += SJ) {
        // ---- stage: pure contiguous copy (8 KB hi + 8 KB lo + scalars) ----
        const uint4* srcH = (const uint4*)(gHi + (size_t)(s >> 4) * 512);
        const uint4* srcL = (const uint4*)(gLo + (size_t)(s >> 4) * 512);
        uint4* dstH = (uint4*)sHi;
        uint4* dstL = (uint4*)sLo;
        dstH[tid]       = srcH[tid];
        dstH[tid + 256] = srcH[tid + 256];
        dstL[tid]       = srcL[tid];
        dstL[tid + 256] = srcL[tid + 256];
        if (tid < SJ) {
            sXJ[tid] = xpb[s + tid];
            sFN[tid] = fnb[s + tid];
        }
        __syncthreads();

        // ---- compute: 8 16x16 pair tiles ----
#pragma unroll 2
        for (int jt8 = 0; jt8 < SJ/16; ++jt8) {
            const short8 Ahi = *(const short8*)&sHi[(jt8 * 64 + lane) * 8];
            const short8 Alo = *(const short8*)&sLo[(jt8 * 64 + lane) * 8];
            floatx4 c = {0.f, 0.f, 0.f, 0.f};
            c = __builtin_amdgcn_mfma_f32_16x16x32_bf16(F1hi, Ahi, c, 0, 0, 0);
            c = __builtin_amdgcn_mfma_f32_16x16x32_bf16(F1hi, Alo, c, 0, 0, 0);
            c = __builtin_amdgcn_mfma_f32_16x16x32_bf16(F1lo, Ahi, c, 0, 0, 0);

            const int jl = jt8 * 16 + m;       // this lane's single j
            float4 xj = sXJ[jl];               // (x,y,z,-w)
            float fnj = sFN[jl];               // -f2n
            v2f xjx = {xj.x, xj.x};
            v2f xjy = {xj.y, xj.y};
            v2f xjz = {xj.z, xj.z};
            v2f xjw = {xj.w, xj.w};
            v2f fn2 = {fnj, fnj};

#pragma unroll
            for (int g = 0; g < 2; ++g) {
                v2f c2; c2.x = c[2*g]; c2.y = c[2*g + 1];
                v2f t0 = __builtin_elementwise_fma(xjx, vxx[g], vmw[g]);
                t0 = __builtin_elementwise_fma(xjy, vxy[g], t0);
                t0 = __builtin_elementwise_fma(xjz, vxz[g], t0);
                v2f aL = t0 + xjw;                               // log2 spatial
                v2f bL = __builtin_elementwise_fma(c2, vL2, vnf[g] + fn2);
                v2f ea; ea.x = fast_exp2(aL.x); ea.y = fast_exp2(aL.y);
                v2f eb; eb.x = fast_exp2(bL.x); eb.y = fast_exp2(bL.y);
                sA2[g] += ea;
                sB2[g] += eb;
                s2a2[g] = __builtin_elementwise_fma(ea, ea, s2a2[g]);
                s2b2[g] = __builtin_elementwise_fma(eb, eb, s2b2[g]);
                sab2[g] = __builtin_elementwise_fma(ea, eb, sab2[g]);
            }
        }
        __syncthreads();
    }

    // ---- reduce over m: one xor-8 fold, then LDS transpose ----
#define F8(v) do { v.x += __shfl_xor(v.x, 8); v.y += __shfl_xor(v.y, 8); } while (0)
    F8(sA2[0]);  F8(sA2[1]);
    F8(s2a2[0]); F8(s2a2[1]);
    F8(sB2[0]);  F8(sB2[1]);
    F8(s2b2[0]); F8(s2b2[1]);
    F8(sab2[0]); F8(sab2[1]);
#undef F8

    // sRED layout: row rr = (wv*4+q)*5 + qty, 40 floats/row (160 B, padded
    // for bank spread), col m*4: float4 = i rows (q*4 .. q*4+3).
    if (m < 8) {
        float* base = sRED + (size_t)((wv*4 + q) * 5) * 40 + m * 4;
        float4 t;
        t.x=sA2[0].x;  t.y=sA2[0].y;  t.z=sA2[1].x;  t.w=sA2[1].y;  *(float4*)(base + 0*40) = t;
        t.x=s2a2[0].x; t.y=s2a2[0].y; t.z=s2a2[1].x; t.w=s2a2[1].y; *(float4*)(base + 1*40) = t;
        t.x=sB2[0].x;  t.y=sB2[0].y;  t.z=sB2[1].x;  t.w=sB2[1].y;  *(float4*)(base + 2*40) = t;
        t.x=s2b2[0].x; t.y=s2b2[0].y; t.z=s2b2[1].x; t.w=s2b2[1].y; *(float4*)(base + 3*40) = t;
        t.x=sab2[0].x; t.y=sab2[0].y; t.z=sab2[1].x; t.w=sab2[1].y; *(float4*)(base + 4*40) = t;
    }
    __syncthreads();

    if (tid < 80) {                            // 16 i-quads x 5 quantities
        const float* rbase = sRED + (size_t)tid * 40;
        float4 sm = *(const float4*)(rbase);
#pragma unroll
        for (int mm = 1; mm < 8; ++mm) {
            float4 t = *(const float4*)(rbase + mm * 4);
            sm.x += t.x; sm.y += t.y; sm.z += t.z; sm.w += t.w;
        }
        int iq  = tid / 5;
        int qty = tid - iq * 5;
        int row = blockIdx.x * 64 + iq * 4;
        float* ap = acc + (size_t)qty * BN + row;
        atomicAdd(ap + 0, sm.x);
        atomicAdd(ap + 1, sm.y);
        atomicAdd(ap + 2, sm.z);
        atomicAdd(ap + 3, sm.w);
    }
}

// ---------------------------------------------------------------------------
// Kernel B: combine per-row sums, weight, reduce into out[b] (out zeroed by P).
//   out[b] = sum_i w_i * ( S2a/A^2 - 2*Sab/(A*B) + S2b/B^2 )
// ---------------------------------------------------------------------------
__global__ __launch_bounds__(BLK) void finalize_kernel(
    const float* __restrict__ acc,
    const float* __restrict__ weights,
    float* __restrict__ out,
    int N, int BN)
{
    int row = blockIdx.x * BLK + threadIdx.x;
    int b   = (blockIdx.x * BLK) / N;

    float A   = acc[0*BN + row];
    float S2a = acc[1*BN + row];
    float Bt  = acc[2*BN + row];
    float S2b = acc[3*BN + row];
    float Sab = acc[4*BN + row];
    float invA = 1.0f / A;
    float invB = 1.0f / Bt;
    float val  = S2a*invA*invA - 2.0f*Sab*invA*invB + S2b*invB*invB;
    float sum  = weights[row] * val;

    __shared__ float red[BLK/64];
    for (int off = 32; off > 0; off >>= 1)
        sum += __shfl_down(sum, off);
    if ((threadIdx.x & 63) == 0) red[threadIdx.x >> 6] = sum;
    __syncthreads();
    if (threadIdx.x == 0) {
        float s = 0.f;
#pragma unroll
        for (int w = 0; w < BLK/64; ++w) s += red[w];
        atomicAdd(&out[b], s);
    }
}

// ---------------------------------------------------------------------------
extern "C" void kernel_launch(void* const* d_in, const int* in_sizes, int n_in,
                              void* d_out, int out_size, void* d_ws, size_t ws_size,
                              hipStream_t stream) {
    const float* points  = (const float*)d_in[0];
    const float* fea1    = (const float*)d_in[1];
    const float* fea2    = (const float*)d_in[2];
    const float* weights = (const float*)d_in[3];
    float* out = (float*)d_out;

    int B  = out_size;          // 2
    int BN = in_sizes[3];       // B*N = 8192
    int N  = BN / B;            // 4096

    // workspace (bytes):
    //   acc  : 5*BN*4   @ 0
    //   xp4  : 4*BN*4   @ 5*BN*4
    //   mfn  : BN*4     @ 9*BN*4
    //   f1n  : BN*4     @ 10*BN*4
    //   f2hi : BN*D*2   @ 11*BN*4
    //   f2lo : BN*D*2
    float*  acc  = (float*)d_ws;
    float4* xp4  = (float4*)((char*)d_ws + (size_t)5  * BN * 4);
    float*  mfn  = (float*)((char*)d_ws + (size_t)9  * BN * 4);
    float*  f1n  = (float*)((char*)d_ws + (size_t)10 * BN * 4);
    short*  f2hi = (short*)((char*)d_ws + (size_t)11 * BN * 4);
    short*  f2lo = f2hi + (size_t)BN * D;

    precompute_kernel<<<dim3((BN + BLKP - 1) / BLKP), dim3(BLKP), 0, stream>>>(
        points, fea1, fea2, xp4, f1n, mfn, f2hi, f2lo, acc, out, BN, B);

    dim3 grid(BN / 64, NCH);    // 128 x 16 = 2048 blocks (8 blocks/CU)
    pair_kernel<<<grid, dim3(BLK), 0, stream>>>(
        fea1, f2hi, f2lo, xp4, f1n, mfn, acc, N, BN);

    finalize_kernel<<<dim3(BN / BLK), dim3(BLK), 0, stream>>>(acc, weights, out, N, BN);
}

// Round 9
// 84.012 us; speedup vs baseline: 2.1826x; 1.0362x over previous
//
#include <hip/hip_runtime.h>

#define D    32       // feature dim (fixed)
#define BLK  256      // threads per block (4 waves, 64 i-rows per block)
#define BLKP 64       // precompute block (wide grid: latency-bound kernel)
#define NCH  16       // j-chunks per batch -> grid.y
#define SJ   128      // j-rows staged in LDS per stage (8 MFMA tiles)

#define LOG2E 1.44269504088896340736f

typedef short  short8  __attribute__((ext_vector_type(8)));
typedef float  floatx4 __attribute__((ext_vector_type(4)));
typedef float  v2f     __attribute__((ext_vector_type(2)));

__device__ __forceinline__ short f2bf(float v) {       // fp32 -> bf16 (RTNE-ish)
    union { float f; unsigned u; } x; x.f = v;
    unsigned r = x.u + 0x7fffu + ((x.u >> 16) & 1u);
    return (short)(r >> 16);
}
__device__ __forceinline__ float bf2f(short h) {
    union { float f; unsigned u; } x;
    x.u = ((unsigned)(unsigned short)h) << 16;
    return x.f;
}
__device__ __forceinline__ float fast_exp2(float x) {
#if __has_builtin(__builtin_amdgcn_exp2f)
    return __builtin_amdgcn_exp2f(x);
#else
    return exp2f(x);
#endif
}

// ---------------------------------------------------------------------------
// Kernel P: per-row precompute + zero-init + global bf16 hi/lo split of fea2
// (fragment-major, unchanged) + QUAD-SoA j-scalar pack jpk:
//   per j-quad g (rows 4g..4g+3), 20 floats (80 B, 16B-aligned):
//     [0..3] x0..x3   [4..7] y0..y3   [8..11] z0..z3
//     [12..15] -w0..-w3  (w = log2e*|20p|^2, pre-negated)
//     [16..19] -f0..-f3  (f = log2e*|fea2|^2, pre-negated)
//   -> pair epilogue reads 5 x b128 per tile from ONE base pointer
//      (R6 read 6 ops: 2xb128+2xb128+2xb64). Broadcast across the 16
//      m-lanes (same addr, free); q-lanes land on disjoint bank quads.
//   xp[r] = (20*px,20*py,20*pz, log2e*|20p|^2)  [i-side, w positive]
//   f1n[r] = log2e*|fea1_r|^2                   [i-side]
// ---------------------------------------------------------------------------
__global__ __launch_bounds__(BLKP) void precompute_kernel(
    const float* __restrict__ points,
    const float* __restrict__ fea1,
    const float* __restrict__ fea2,
    float4* __restrict__ xp,
    float* __restrict__ f1n,
    float* __restrict__ jpk,
    short* __restrict__ f2hi,
    short* __restrict__ f2lo,
    float* __restrict__ acc,
    float* __restrict__ out,
    int BN, int Bsz)
{
    int r = blockIdx.x * BLKP + threadIdx.x;
    if (r < Bsz) out[r] = 0.0f;
    if (r >= BN) return;
#pragma unroll
    for (int s = 0; s < 5; ++s) acc[s * BN + r] = 0.0f;

    const float s20 = 20.0f;                 // 1/SIGMA
    float x = points[3*r+0] * s20;
    float y = points[3*r+1] * s20;
    float z = points[3*r+2] * s20;
    float4 v; v.x = x; v.y = y; v.z = z;
    v.w = (x*x + y*y + z*z) * LOG2E;
    xp[r] = v;

    // f1 norm
    const float4* p1 = (const float4*)(fea1 + (size_t)r * D);
    float n1 = 0.f;
#pragma unroll
    for (int k = 0; k < D/4; ++k) {
        float4 a = p1[k];
        n1 = fmaf(a.x,a.x, fmaf(a.y,a.y, fmaf(a.z,a.z, fmaf(a.w,a.w, n1))));
    }
    f1n[r] = n1 * LOG2E;

    // f2: norm + hi/lo split, scattered fragment-major
    const int t = r >> 4;                    // global 16-row tile id
    const int m = r & 15;
    const float* p2 = fea2 + (size_t)r * D;
    float n2 = 0.f;
#pragma unroll
    for (int q = 0; q < 4; ++q) {
        float4 v0 = *(const float4*)(p2 + q*8);
        float4 v1 = *(const float4*)(p2 + q*8 + 4);
        float e[8] = {v0.x,v0.y,v0.z,v0.w,v1.x,v1.y,v1.z,v1.w};
        short8 h, l;
#pragma unroll
        for (int k = 0; k < 8; ++k) {
            n2 = fmaf(e[k], e[k], n2);
            short hh = f2bf(e[k]);
            h[k] = hh;
            l[k] = f2bf(e[k] - bf2f(hh));
        }
        size_t off = ((size_t)t * 64 + m + 16*q) * 8;
        *(short8*)&f2hi[off] = h;
        *(short8*)&f2lo[off] = l;
    }

    // quad-SoA j-scalar pack
    float* jb = jpk + (size_t)(r >> 2) * 20 + (r & 3);
    jb[0]  = v.x;
    jb[4]  = v.y;
    jb[8]  = v.z;
    jb[12] = -v.w;
    jb[16] = -n2 * LOG2E;
}

// ---------------------------------------------------------------------------
// Kernel A: pair loop -- R6 (82.55us best) structure verbatim, EXCEPT the
// j-scalar LDS pack: quad-SoA sJP, 5 x b128 reads per tile (was 6 ops).
//   Mapping (R6/baseline): A = f2 (LDS frags, rows=j), B = f1 (reg frags,
//   cols=i); C col = lane&15 = i, row = q*4+r = j.  pk (v_pk_fma_f32)
//   epilogue on (r=2h, r=2h+1) pairs; per-pair arithmetic bit-identical
//   to R6 (same fma/exp chains); only the LDS access shape changed.
//   Registers ~58 (R6-equal +0): fits the 64-VGPR (256,8) cap -- no spill
//   (R7 lesson: the cap + >64 live set = scratch catastrophe; R6 proved
//   this live set fits).
// ---------------------------------------------------------------------------
__global__ __launch_bounds__(BLK, 8) void pair_kernel(
    const float* __restrict__ fea1,
    const short* __restrict__ f2hi,
    const short* __restrict__ f2lo,
    const float* __restrict__ jpk,
    const float4* __restrict__ xp,
    const float* __restrict__ f1n,
    float* __restrict__ acc,
    int N, int BN)
{
    __shared__ __align__(16) short sHi[SJ * D];      // 8 KB, fragment-major
    __shared__ __align__(16) short sLo[SJ * D];      // 8 KB
    __shared__ __align__(16) float sJP[(SJ/4) * 20]; // 2.5 KB quad j-scalars

    const int tid  = threadIdx.x;
    const int lane = tid & 63;
    const int wv   = tid >> 6;
    const int m    = lane & 15;        // i-offset (B n-index / C col)
    const int q    = lane >> 4;        // k-octet / j-quad

    const int ibpb  = N / 64;          // i-blocks per batch
    const int b     = blockIdx.x / ibpb;
    const int ibase = blockIdx.x * 64 + wv * 16;
    const int JCH   = N / NCH;
    const int jc0   = blockIdx.y * JCH;

    // ---- B fragments: f1 rows of this wave's 16 i's, split hi/lo ----
    const float* f1p = fea1 + (size_t)(ibase + m) * D + q * 8;
    float4 bv0 = *(const float4*)(f1p);
    float4 bv1 = *(const float4*)(f1p + 4);
    float bf[8] = {bv0.x,bv0.y,bv0.z,bv0.w,bv1.x,bv1.y,bv1.z,bv1.w};
    short8 Bhi, Blo;
#pragma unroll
    for (int k = 0; k < 8; ++k) {
        short h = f2bf(bf[k]);
        Bhi[k] = h;
        Blo[k] = f2bf(bf[k] - bf2f(h));
    }

    const float L2 = 2.0f * LOG2E;
    float4 xi = xp[ibase + m];
    float nfi = -f1n[ibase + m];       // -log2e*|f1_i|^2
    v2f vxx2 = {xi.x * L2, xi.x * L2};
    v2f vxy2 = {xi.y * L2, xi.y * L2};
    v2f vxz2 = {xi.z * L2, xi.z * L2};
    v2f vmw2 = {-xi.w, -xi.w};
    v2f vnf2 = {nfi, nfi};
    v2f vL2  = {L2, L2};

    // accumulators (x-half: even r; y-half: odd r)
    v2f sA2  = {0.f, 0.f};
    v2f sB2  = {0.f, 0.f};
    v2f s2a2 = {0.f, 0.f};
    v2f s2b2 = {0.f, 0.f};
    v2f sab2 = {0.f, 0.f};

    const short* gHi = f2hi + ((size_t)(b * N + jc0) >> 4) * 512;
    const short* gLo = f2lo + ((size_t)(b * N + jc0) >> 4) * 512;
    const float* gJP = jpk  + ((size_t)(b * N + jc0) >> 2) * 20;

    for (int s = 0; s < JCH; s += SJ) {
        // ---- stage: pure contiguous copies ----
        const uint4* srcH = (const uint4*)(gHi + (size_t)(s >> 4) * 512);
        const uint4* srcL = (const uint4*)(gLo + (size_t)(s >> 4) * 512);
        const uint4* srcJ = (const uint4*)(gJP + (size_t)(s >> 2) * 20);
        uint4* dstH = (uint4*)sHi;
        uint4* dstL = (uint4*)sLo;
        dstH[tid]       = srcH[tid];
        dstH[tid + 256] = srcH[tid + 256];
        dstL[tid]       = srcL[tid];
        dstL[tid + 256] = srcL[tid + 256];
        if (tid < (SJ/4) * 20 * 4 / 16)              // 160 uint4 = 2.5 KB
            ((uint4*)sJP)[tid] = srcJ[tid];
        __syncthreads();

        // ---- compute: 8 16x16 pair tiles ----
#pragma unroll 2
        for (int jt8 = 0; jt8 < SJ/16; ++jt8) {
            const short8 Ahi = *(const short8*)&sHi[(jt8 * 64 + lane) * 8];
            const short8 Alo = *(const short8*)&sLo[(jt8 * 64 + lane) * 8];
            floatx4 c = {0.f, 0.f, 0.f, 0.f};
            c = __builtin_amdgcn_mfma_f32_16x16x32_bf16(Ahi, Bhi, c, 0, 0, 0);
            c = __builtin_amdgcn_mfma_f32_16x16x32_bf16(Ahi, Blo, c, 0, 0, 0);
            c = __builtin_amdgcn_mfma_f32_16x16x32_bf16(Alo, Bhi, c, 0, 0, 0);

            // this lane's j-quad scalars: 5 x b128 at immediate offsets
            const float* pj = sJP + (jt8 * 4 + q) * 20;
            float4 X = *(const float4*)(pj);          // x0..x3
            float4 Y = *(const float4*)(pj + 4);      // y0..y3
            float4 Z = *(const float4*)(pj + 8);      // z0..z3
            float4 W = *(const float4*)(pj + 12);     // -w0..-w3
            float4 F = *(const float4*)(pj + 16);     // -f0..-f3

#pragma unroll
            for (int h = 0; h < 2; ++h) {
                v2f xx = h ? (v2f){X.z, X.w} : (v2f){X.x, X.y};
                v2f yy = h ? (v2f){Y.z, Y.w} : (v2f){Y.x, Y.y};
                v2f zz = h ? (v2f){Z.z, Z.w} : (v2f){Z.x, Z.y};
                v2f wn = h ? (v2f){W.z, W.w} : (v2f){W.x, W.y};
                v2f fn = h ? (v2f){F.z, F.w} : (v2f){F.x, F.y};
                v2f c2 = {c[2*h], c[2*h + 1]};
                v2f t0 = __builtin_elementwise_fma(xx, vxx2, vmw2);
                t0 = __builtin_elementwise_fma(yy, vxy2, t0);
                t0 = __builtin_elementwise_fma(zz, vxz2, t0);
                v2f aL = t0 + wn;                               // log2 spatial
                v2f bL = __builtin_elementwise_fma(c2, vL2, vnf2 + fn); // log2 feat
                v2f ea = {fast_exp2(aL.x), fast_exp2(aL.y)};
                v2f eb = {fast_exp2(bL.x), fast_exp2(bL.y)};
                sA2 += ea;
                sB2 += eb;
                s2a2 = __builtin_elementwise_fma(ea, ea, s2a2);
                s2b2 = __builtin_elementwise_fma(eb, eb, s2b2);
                sab2 = __builtin_elementwise_fma(ea, eb, sab2);
            }
        }
        __syncthreads();
    }

    // fold the even/odd-r partial sums
    float vA  = sA2.x  + sA2.y;
    float vB  = sB2.x  + sB2.y;
    float v2a = s2a2.x + s2a2.y;
    float v2b = s2b2.x + s2b2.y;
    float vab = sab2.x + sab2.y;

    // ---- reduce the 4 j-quads (lanes sharing lane&15) ----
    vA  += __shfl_xor(vA, 16);  vA  += __shfl_xor(vA, 32);
    vB  += __shfl_xor(vB, 16);  vB  += __shfl_xor(vB, 32);
    v2a += __shfl_xor(v2a, 16); v2a += __shfl_xor(v2a, 32);
    v2b += __shfl_xor(v2b, 16); v2b += __shfl_xor(v2b, 32);
    vab += __shfl_xor(vab, 16); vab += __shfl_xor(vab, 32);

    if (lane < 16) {
        int row = ibase + lane;
        atomicAdd(&acc[0*BN + row], vA);
        atomicAdd(&acc[1*BN + row], v2a);
        atomicAdd(&acc[2*BN + row], vB);
        atomicAdd(&acc[3*BN + row], v2b);
        atomicAdd(&acc[4*BN + row], vab);
    }
}

// ---------------------------------------------------------------------------
// Kernel B: combine per-row sums, weight, reduce into out[b] (out zeroed by P).
//   out[b] = sum_i w_i * ( S2a/A^2 - 2*Sab/(A*B) + S2b/B^2 )
// ---------------------------------------------------------------------------
__global__ __launch_bounds__(BLK) void finalize_kernel(
    const float* __restrict__ acc,
    const float* __restrict__ weights,
    float* __restrict__ out,
    int N, int BN)
{
    int row = blockIdx.x * BLK + threadIdx.x;
    int b   = (blockIdx.x * BLK) / N;

    float A   = acc[0*BN + row];
    float S2a = acc[1*BN + row];
    float Bt  = acc[2*BN + row];
    float S2b = acc[3*BN + row];
    float Sab = acc[4*BN + row];
    float invA = 1.0f / A;
    float invB = 1.0f / Bt;
    float val  = S2a*invA*invA - 2.0f*Sab*invA*invB + S2b*invB*invB;
    float sum  = weights[row] * val;

    __shared__ float red[BLK/64];
    for (int off = 32; off > 0; off >>= 1)
        sum += __shfl_down(sum, off);
    if ((threadIdx.x & 63) == 0) red[threadIdx.x >> 6] = sum;
    __syncthreads();
    if (threadIdx.x == 0) {
        float s = 0.f;
#pragma unroll
        for (int w = 0; w < BLK/64; ++w) s += red[w];
        atomicAdd(&out[b], s);
    }
}

// ---------------------------------------------------------------------------
extern "C" void kernel_launch(void* const* d_in, const int* in_sizes, int n_in,
                              void* d_out, int out_size, void* d_ws, size_t ws_size,
                              hipStream_t stream) {
    const float* points  = (const float*)d_in[0];
    const float* fea1    = (const float*)d_in[1];
    const float* fea2    = (const float*)d_in[2];
    const float* weights = (const float*)d_in[3];
    float* out = (float*)d_out;

    int B  = out_size;          // 2
    int BN = in_sizes[3];       // B*N = 8192
    int N  = BN / B;            // 4096

    // workspace (bytes):
    //   acc  : 5*BN*4   @ 0
    //   xp   : 4*BN*4   @ 5*BN*4
    //   f1n  : BN*4     @ 9*BN*4
    //   jpk  : 5*BN*4   @ 10*BN*4   ((BN/4) quads * 20 floats)
    //   f2hi : BN*D*2   @ 15*BN*4
    //   f2lo : BN*D*2
    float*  acc  = (float*)d_ws;
    float4* xp   = (float4*)((char*)d_ws + (size_t)5  * BN * 4);
    float*  f1n  = (float*)((char*)d_ws + (size_t)9  * BN * 4);
    float*  jpk  = (float*)((char*)d_ws + (size_t)10 * BN * 4);
    short*  f2hi = (short*)((char*)d_ws + (size_t)15 * BN * 4);
    short*  f2lo = f2hi + (size_t)BN * D;

    precompute_kernel<<<dim3((BN + BLKP - 1) / BLKP), dim3(BLKP), 0, stream>>>(
        points, fea1, fea2, xp, f1n, jpk, f2hi, f2lo, acc, out, BN, B);

    dim3 grid(BN / 64, NCH);    // 128 x 16 = 2048 blocks (8 blocks/CU)
    pair_kernel<<<grid, dim3(BLK), 0, stream>>>(
        fea1, f2hi, f2lo, jpk, xp, f1n, acc, N, BN);

    finalize_kernel<<<dim3(BN / BLK), dim3(BLK), 0, stream>>>(acc, weights, out, N, BN);
}

// Round 10
// 82.408 us; speedup vs baseline: 2.2251x; 1.0195x over previous
//
#include <hip/hip_runtime.h>

#define D    32       // feature dim (fixed)
#define BLK  256      // threads per block (4 waves, 64 i-rows per block)
#define BLKP 64       // precompute block (wide grid: latency-bound kernel)
#define NCH  16       // j-chunks per batch -> grid.y
#define SJ   128      // j-rows staged in LDS per stage (8 MFMA tiles)

#define LOG2E 1.44269504088896340736f

typedef short  short8  __attribute__((ext_vector_type(8)));
typedef float  floatx4 __attribute__((ext_vector_type(4)));
typedef float  v2f     __attribute__((ext_vector_type(2)));

__device__ __forceinline__ short f2bf(float v) {       // fp32 -> bf16 (RTNE-ish)
    union { float f; unsigned u; } x; x.f = v;
    unsigned r = x.u + 0x7fffu + ((x.u >> 16) & 1u);
    return (short)(r >> 16);
}
__device__ __forceinline__ float bf2f(short h) {
    union { float f; unsigned u; } x;
    x.u = ((unsigned)(unsigned short)h) << 16;
    return x.f;
}
__device__ __forceinline__ float fast_exp2(float x) {
#if __has_builtin(__builtin_amdgcn_exp2f)
    return __builtin_amdgcn_exp2f(x);
#else
    return exp2f(x);
#endif
}

// ---------------------------------------------------------------------------
// Kernel P: per-row precompute + zero-init + global bf16 hi/lo split of fea2
// (fragment-major, unchanged from baseline) + PAIRED-SoA j-scalar pack jpk:
//   per j-pair p (rows 2p,2p+1), 12 floats (48 B, 16B-aligned):
//     [0..3]  x0 x1 y0 y1          (x,y = 20*p)
//     [4..7]  z0 z1 -w0 -w1        (w = log2e*|20p|^2, stored negated)
//     [8..9] -f0 -f1  [10..11] pad (f = log2e*|fea2|^2, stored negated)
//   -> the pair kernel's pk-epilogue reads 2xb128+1xb64 per 2 pairs and the
//      v2f halves come out PRE-PAIRED (zero packing moves -- R9 lesson: the
//      5-op quad layout needed extract movs and lost its LDS saving).
// ---------------------------------------------------------------------------
__global__ __launch_bounds__(BLKP) void precompute_kernel(
    const float* __restrict__ points,
    const float* __restrict__ fea1,
    const float* __restrict__ fea2,
    float4* __restrict__ xp,
    float* __restrict__ f1n,
    float* __restrict__ jpk,
    short* __restrict__ f2hi,
    short* __restrict__ f2lo,
    float* __restrict__ acc,
    float* __restrict__ out,
    int BN, int Bsz)
{
    int r = blockIdx.x * BLKP + threadIdx.x;
    if (r < Bsz) out[r] = 0.0f;
    if (r >= BN) return;
#pragma unroll
    for (int s = 0; s < 5; ++s) acc[s * BN + r] = 0.0f;

    const float s20 = 20.0f;                 // 1/SIGMA
    float x = points[3*r+0] * s20;
    float y = points[3*r+1] * s20;
    float z = points[3*r+2] * s20;
    float4 v; v.x = x; v.y = y; v.z = z;
    v.w = (x*x + y*y + z*z) * LOG2E;
    xp[r] = v;

    // f1 norm
    const float4* p1 = (const float4*)(fea1 + (size_t)r * D);
    float n1 = 0.f;
#pragma unroll
    for (int k = 0; k < D/4; ++k) {
        float4 a = p1[k];
        n1 = fmaf(a.x,a.x, fmaf(a.y,a.y, fmaf(a.z,a.z, fmaf(a.w,a.w, n1))));
    }
    f1n[r] = n1 * LOG2E;

    // f2: norm + hi/lo split, scattered fragment-major
    const int t = r >> 4;                    // global 16-row tile id
    const int m = r & 15;
    const float* p2 = fea2 + (size_t)r * D;
    float n2 = 0.f;
#pragma unroll
    for (int q = 0; q < 4; ++q) {
        float4 v0 = *(const float4*)(p2 + q*8);
        float4 v1 = *(const float4*)(p2 + q*8 + 4);
        float e[8] = {v0.x,v0.y,v0.z,v0.w,v1.x,v1.y,v1.z,v1.w};
        short8 h, l;
#pragma unroll
        for (int k = 0; k < 8; ++k) {
            n2 = fmaf(e[k], e[k], n2);
            short hh = f2bf(e[k]);
            h[k] = hh;
            l[k] = f2bf(e[k] - bf2f(hh));
        }
        size_t off = ((size_t)t * 64 + m + 16*q) * 8;
        *(short8*)&f2hi[off] = h;
        *(short8*)&f2lo[off] = l;
    }

    // paired-SoA j-scalar pack
    float* jb = jpk + (size_t)(r >> 1) * 12 + (r & 1);
    jb[0] = v.x;
    jb[2] = v.y;
    jb[4] = v.z;
    jb[6] = -v.w;
    jb[8] = -n2 * LOG2E;
}

// ---------------------------------------------------------------------------
// Kernel A: pair loop -- the verified session best (82.55 us total, R6).
//   Baseline LDS-staged structure + PACKED (v_pk_f32) epilogue.
//   Per 16x16 tile each lane handles 4 pairs (rows r=0..3, one i-col).
//   c[2h],c[2h+1] are adjacent MFMA result regs -> natural v2f pairs; the
//   j-scalars arrive pre-paired from sJP (2xb128+1xb64 per 2 pairs).
//   [Session history: R2 global-stream 97us; R3 swapped+shuffle-reduce 89;
//    R5 L1 j-scalars 92; R7 swapped+(256,8) spill 183; R8 swapped uncapped
//    87; R9 quad-SoA 84 -- every structural departure from this shape lost.
//    Pair here ~20-21us of which ~13-15 is the LDS-structural floor.]
// ---------------------------------------------------------------------------
__global__ __launch_bounds__(BLK, 8) void pair_kernel(
    const float* __restrict__ fea1,
    const short* __restrict__ f2hi,
    const short* __restrict__ f2lo,
    const float* __restrict__ jpk,
    const float4* __restrict__ xp,
    const float* __restrict__ f1n,
    float* __restrict__ acc,
    int N, int BN)
{
    __shared__ __align__(16) short sHi[SJ * D];   // 8 KB, fragment-major
    __shared__ __align__(16) short sLo[SJ * D];   // 8 KB
    __shared__ __align__(16) float sJP[(SJ/2) * 12]; // 3 KB paired j-scalars

    const int tid  = threadIdx.x;
    const int lane = tid & 63;
    const int wv   = tid >> 6;
    const int m    = lane & 15;        // i-offset (B n-index / C col)
    const int q    = lane >> 4;        // k-octet / j-quad

    const int ibpb  = N / 64;          // i-blocks per batch
    const int b     = blockIdx.x / ibpb;
    const int ibase = blockIdx.x * 64 + wv * 16;
    const int JCH   = N / NCH;
    const int jc0   = blockIdx.y * JCH;

    // ---- B fragments: f1 rows of this wave's 16 i's, split hi/lo ----
    const float* f1p = fea1 + (size_t)(ibase + m) * D + q * 8;
    float4 bv0 = *(const float4*)(f1p);
    float4 bv1 = *(const float4*)(f1p + 4);
    float bf[8] = {bv0.x,bv0.y,bv0.z,bv0.w,bv1.x,bv1.y,bv1.z,bv1.w};
    short8 Bhi, Blo;
#pragma unroll
    for (int k = 0; k < 8; ++k) {
        short h = f2bf(bf[k]);
        Bhi[k] = h;
        Blo[k] = f2bf(bf[k] - bf2f(h));
    }

    const float L2 = 2.0f * LOG2E;
    float4 xi = xp[ibase + m];
    float nfi = -f1n[ibase + m];       // -log2e*|f1_i|^2
    v2f vxx2 = {xi.x * L2, xi.x * L2};
    v2f vxy2 = {xi.y * L2, xi.y * L2};
    v2f vxz2 = {xi.z * L2, xi.z * L2};
    v2f vmw2 = {-xi.w, -xi.w};
    v2f vnf2 = {nfi, nfi};
    v2f vL2  = {L2, L2};

    // accumulators (x-half: even r; y-half: odd r)
    v2f sA2  = {0.f, 0.f};
    v2f sB2  = {0.f, 0.f};
    v2f s2a2 = {0.f, 0.f};
    v2f s2b2 = {0.f, 0.f};
    v2f sab2 = {0.f, 0.f};

    const short* gHi = f2hi + ((size_t)(b * N + jc0) >> 4) * 512;
    const short* gLo = f2lo + ((size_t)(b * N + jc0) >> 4) * 512;
    const float* gJP = jpk  + ((size_t)(b * N + jc0) >> 1) * 12;

    for (int s = 0; s < JCH; s += SJ) {
        // ---- stage: pure contiguous copies ----
        const uint4* srcH = (const uint4*)(gHi + (size_t)(s >> 4) * 512);
        const uint4* srcL = (const uint4*)(gLo + (size_t)(s >> 4) * 512);
        const uint4* srcJ = (const uint4*)(gJP + (size_t)(s >> 1) * 12);
        uint4* dstH = (uint4*)sHi;
        uint4* dstL = (uint4*)sLo;
        dstH[tid]       = srcH[tid];
        dstH[tid + 256] = srcH[tid + 256];
        dstL[tid]       = srcL[tid];
        dstL[tid + 256] = srcL[tid + 256];
        if (tid < (SJ/2) * 12 * 4 / 16)              // 192 uint4 = 3 KB
            ((uint4*)sJP)[tid] = srcJ[tid];
        __syncthreads();

        // ---- compute: 8 16x16 pair tiles ----
#pragma unroll 2
        for (int jt8 = 0; jt8 < SJ/16; ++jt8) {
            const short8 Ahi = *(const short8*)&sHi[(jt8 * 64 + lane) * 8];
            const short8 Alo = *(const short8*)&sLo[(jt8 * 64 + lane) * 8];
            floatx4 c = {0.f, 0.f, 0.f, 0.f};
            c = __builtin_amdgcn_mfma_f32_16x16x32_bf16(Ahi, Bhi, c, 0, 0, 0);
            c = __builtin_amdgcn_mfma_f32_16x16x32_bf16(Ahi, Blo, c, 0, 0, 0);
            c = __builtin_amdgcn_mfma_f32_16x16x32_bf16(Alo, Bhi, c, 0, 0, 0);
#pragma unroll
            for (int h = 0; h < 2; ++h) {
                const int jp = jt8 * 8 + q * 2 + h;   // pair idx (j=2jp,2jp+1)
                float4 XY = *(const float4*)&sJP[jp * 12 + 0];
                float4 ZW = *(const float4*)&sJP[jp * 12 + 4];
                v2f    Fn = *(const v2f*)  &sJP[jp * 12 + 8];
                v2f xx = {XY.x, XY.y};
                v2f yy = {XY.z, XY.w};
                v2f zz = {ZW.x, ZW.y};
                v2f wn = {ZW.z, ZW.w};                // -xj.w (pre-negated)
                v2f c2 = {c[2*h], c[2*h + 1]};
                v2f t0 = __builtin_elementwise_fma(xx, vxx2, vmw2);
                t0 = __builtin_elementwise_fma(yy, vxy2, t0);
                t0 = __builtin_elementwise_fma(zz, vxz2, t0);
                v2f aL = t0 + wn;                               // log2 spatial
                v2f bL = __builtin_elementwise_fma(c2, vL2, vnf2 + Fn); // log2 feat
                v2f ea = {fast_exp2(aL.x), fast_exp2(aL.y)};
                v2f eb = {fast_exp2(bL.x), fast_exp2(bL.y)};
                sA2 += ea;
                sB2 += eb;
                s2a2 = __builtin_elementwise_fma(ea, ea, s2a2);
                s2b2 = __builtin_elementwise_fma(eb, eb, s2b2);
                sab2 = __builtin_elementwise_fma(ea, eb, sab2);
            }
        }
        __syncthreads();
    }

    // fold the even/odd-r partial sums
    float vA  = sA2.x  + sA2.y;
    float vB  = sB2.x  + sB2.y;
    float v2a = s2a2.x + s2a2.y;
    float v2b = s2b2.x + s2b2.y;
    float vab = sab2.x + sab2.y;

    // ---- reduce the 4 j-quads (lanes sharing lane&15) ----
    vA  += __shfl_xor(vA, 16);  vA  += __shfl_xor(vA, 32);
    vB  += __shfl_xor(vB, 16);  vB  += __shfl_xor(vB, 32);
    v2a += __shfl_xor(v2a, 16); v2a += __shfl_xor(v2a, 32);
    v2b += __shfl_xor(v2b, 16); v2b += __shfl_xor(v2b, 32);
    vab += __shfl_xor(vab, 16); vab += __shfl_xor(vab, 32);

    if (lane < 16) {
        int row = ibase + lane;
        atomicAdd(&acc[0*BN + row], vA);
        atomicAdd(&acc[1*BN + row], v2a);
        atomicAdd(&acc[2*BN + row], vB);
        atomicAdd(&acc[3*BN + row], v2b);
        atomicAdd(&acc[4*BN + row], vab);
    }
}

// ---------------------------------------------------------------------------
// Kernel B: combine per-row sums, weight, reduce into out[b] (out zeroed by P).
//   out[b] = sum_i w_i * ( S2a/A^2 - 2*Sab/(A*B) + S2b/B^2 )
// ---------------------------------------------------------------------------
__global__ __launch_bounds__(BLK) void finalize_kernel(
    const float* __restrict__ acc,
    const float* __restrict__ weights,
    float* __restrict__ out,
    int N, int BN)
{
    int row = blockIdx.x * BLK + threadIdx.x;
    int b   = (blockIdx.x * BLK) / N;

    float A   = acc[0*BN + row];
    float S2a = acc[1*BN + row];
    float Bt  = acc[2*BN + row];
    float S2b = acc[3*BN + row];
    float Sab = acc[4*BN + row];
    float invA = 1.0f / A;
    float invB = 1.0f / Bt;
    float val  = S2a*invA*invA - 2.0f*Sab*invA*invB + S2b*invB*invB;
    float sum  = weights[row] * val;

    __shared__ float red[BLK/64];
    for (int off = 32; off > 0; off >>= 1)
        sum += __shfl_down(sum, off);
    if ((threadIdx.x & 63) == 0) red[threadIdx.x >> 6] = sum;
    __syncthreads();
    if (threadIdx.x == 0) {
        float s = 0.f;
#pragma unroll
        for (int w = 0; w < BLK/64; ++w) s += red[w];
        atomicAdd(&out[b], s);
    }
}

// ---------------------------------------------------------------------------
extern "C" void kernel_launch(void* const* d_in, const int* in_sizes, int n_in,
                              void* d_out, int out_size, void* d_ws, size_t ws_size,
                              hipStream_t stream) {
    const float* points  = (const float*)d_in[0];
    const float* fea1    = (const float*)d_in[1];
    const float* fea2    = (const float*)d_in[2];
    const float* weights = (const float*)d_in[3];
    float* out = (float*)d_out;

    int B  = out_size;          // 2
    int BN = in_sizes[3];       // B*N = 8192
    int N  = BN / B;            // 4096

    // workspace (bytes):
    //   acc  : 5*BN*4   @ 0
    //   xp   : 4*BN*4   @ 5*BN*4
    //   f1n  : BN*4     @ 9*BN*4
    //   jpk  : 6*BN*4   @ 10*BN*4   ((BN/2) pairs * 12 floats)
    //   f2hi : BN*D*2   @ 16*BN*4
    //   f2lo : BN*D*2
    float*  acc  = (float*)d_ws;
    float4* xp   = (float4*)((char*)d_ws + (size_t)5  * BN * 4);
    float*  f1n  = (float*)((char*)d_ws + (size_t)9  * BN * 4);
    float*  jpk  = (float*)((char*)d_ws + (size_t)10 * BN * 4);
    short*  f2hi = (short*)((char*)d_ws + (size_t)16 * BN * 4);
    short*  f2lo = f2hi + (size_t)BN * D;

    precompute_kernel<<<dim3((BN + BLKP - 1) / BLKP), dim3(BLKP), 0, stream>>>(
        points, fea1, fea2, xp, f1n, jpk, f2hi, f2lo, acc, out, BN, B);

    dim3 grid(BN / 64, NCH);    // 128 x 16 = 2048 blocks (8 blocks/CU)
    pair_kernel<<<grid, dim3(BLK), 0, stream>>>(
        fea1, f2hi, f2lo, jpk, xp, f1n, acc, N, BN);

    finalize_kernel<<<dim3(BN / BLK), dim3(BLK), 0, stream>>>(acc, weights, out, N, BN);
}